// Round 4
// baseline (6326.009 us; speedup 1.0000x reference)
//
#include <hip/hip_runtime.h>

// Residual 2-layer LSTM, T=256 B=64 H=1024, fp32 io, bf16 MFMA compute.
// R4: producer/consumer wave specialization. 128 WGs x 512 thr (8 waves,
// 2/SIMD). Waves 0-3 ("x-waves"): elementwise + h-publish + per-wave flag +
// x-GEMM(t+1). Waves 4-7 ("h-waves"): poll ONLY their 32 K-producers (one
// 128B flag line/round), cached h loads, h-MFMA. Double-buffered LDS gate
// partials -> single __syncthreads per step. Weights stay VGPR-resident
// (16 frags/wave). R3 was 10us/step with everything on one serial chain
// behind a 128-producer barrier; this overlaps x-GEMM/tail with the
// publish->poll->h-load RTT and cuts the poll set 4x.

#define TT 256
#define BB 64
#define HH 1024
#define GG 128
#define BH (BB * HH)
#define GPS 35                      // LDS col stride: writes<=3-way, reads 2-way
#define LDS_BYTES (2 * 8 * 64 * GPS * 4) // 143,360 B (dynamic)

typedef __attribute__((ext_vector_type(8))) short short8;
typedef __attribute__((ext_vector_type(4))) float float4v;
typedef __attribute__((ext_vector_type(2))) float float2v;

__device__ __forceinline__ unsigned short f2bf(float f) {
  unsigned u = __builtin_bit_cast(unsigned, f);
  u += 0x7fffu + ((u >> 16) & 1u);
  return (unsigned short)(u >> 16);
}
__device__ __forceinline__ float bf2f(unsigned short s) {
  unsigned u = ((unsigned)s) << 16;
  return __builtin_bit_cast(float, u);
}
__device__ __forceinline__ float fexp2(float x) { return __builtin_amdgcn_exp2f(x); }
__device__ __forceinline__ float frcp(float x) { return __builtin_amdgcn_rcpf(x); }
__device__ __forceinline__ float sigm(float x) {
  return frcp(1.0f + fexp2(-1.4426950408889634f * x));
}
__device__ __forceinline__ float tanha(float x) {
  return 1.0f - 2.0f * frcp(1.0f + fexp2(2.8853900817779268f * x));
}

__global__ __launch_bounds__(256) void cvt_f32_bf16(const float* __restrict__ in,
                                                    unsigned short* __restrict__ out,
                                                    int n8) {
  int i = blockIdx.x * 256 + threadIdx.x;
  if (i >= n8) return;
  const float4v* p = (const float4v*)in + (size_t)i * 2;
  float4v a = p[0], b = p[1];
  short8 v;
  v[0] = (short)f2bf(a[0]); v[1] = (short)f2bf(a[1]);
  v[2] = (short)f2bf(a[2]); v[3] = (short)f2bf(a[3]);
  v[4] = (short)f2bf(b[0]); v[5] = (short)f2bf(b[1]);
  v[6] = (short)f2bf(b[2]); v[7] = (short)f2bf(b[3]);
  ((short8*)out)[i] = v;
}

// gp(par, wave, b, col) in dynamic LDS
#define GP(par, ww, b, c) smem[((((par)*8 + (ww)) * 64 + (b)) * GPS) + (c)]

// Ax layouts: 0 = row-major [t][b][h] bf16 (layer5: xb); 1 = blocked
// [t][col>>3][b][col&7] bf16 (layer6: out5b; same layout as hbuf).
__global__ __launch_bounds__(512, 2) void lstm_layer(
    const unsigned short* __restrict__ Ax, const int xlayout,
    const float* __restrict__ wih, const float* __restrict__ whh,
    const float* __restrict__ bih, const float* __restrict__ bhh,
    const float* __restrict__ resf,          // fp32 row-major residual or null
    const unsigned short* __restrict__ resb, // bf16 blocked residual or null
    unsigned short* __restrict__ outb,       // bf16 blocked out or null
    float* __restrict__ outf,                // fp32 row-major out or null
    unsigned short* __restrict__ hbuf, int* __restrict__ flags) {
  extern __shared__ float smem[];
  const int p = blockIdx.x;
  const int tid = threadIdx.x;
  const int w = tid >> 6;   // 0..7
  const int lane = tid & 63;
  const int ln = lane & 15;
  const int q = lane >> 4;
  const bool xw = (w < 4);  // x-wave vs h-wave
  const int kq = w & 3;     // K-quarter [256*kq, 256*kq+256)

  // ---- persistent weight fragments (16/wave): n = 16*nt+ln,
  // k = 256*kq + kk*32 + 8*q + j
  const float* wmat = xw ? wih : whh;
  short8 wf[16];
#pragma unroll
  for (int kk = 0; kk < 8; ++kk) {
#pragma unroll
    for (int nt = 0; nt < 2; ++nt) {
      const int n = 16 * nt + ln;
      const int gidx = (n >> 3) * HH + p * 8 + (n & 7); // gate order i,f,g,o
      const float* src = wmat + (size_t)gidx * HH + 256 * kq + kk * 32 + 8 * q;
      short8 v;
#pragma unroll
      for (int j = 0; j < 8; ++j) v[j] = (short)f2bf(src[j]);
      wf[kk * 2 + nt] = v;
    }
  }

  // ---- A-operand offsets (x-wave layout 0: row-major; else blocked)
  size_t roff[4], kstep;
  if (xw && xlayout == 0) {
    kstep = 32;
#pragma unroll
    for (int mt = 0; mt < 4; ++mt)
      roff[mt] = (size_t)(16 * mt + ln) * HH + (size_t)(256 * kq + 8 * q);
  } else {
    kstep = 2048;
#pragma unroll
    for (int mt = 0; mt < 4; ++mt)
      roff[mt] = (size_t)(16 * mt + ln) * 8 + (size_t)(256 * kq + 8 * q) * 64;
  }

  // ---- x-wave elementwise state: thread owns (b=lane, cols 2w, 2w+1)
  float bsum[2][4];
  float cst[2] = {0.f, 0.f};
  if (xw) {
#pragma unroll
    for (int s = 0; s < 2; ++s) {
      const int jj = 2 * w + s;
#pragma unroll
      for (int gt = 0; gt < 4; ++gt) {
        const int gidx = gt * HH + p * 8 + jj;
        bsum[s][gt] = bih[gidx] + bhh[gidx];
      }
    }
  }

  float4v acc[4][2];

  // ---- pre-loop: fill gp(par=0): x-waves x-GEMM(0), h-waves zeros
#pragma unroll
  for (int mt = 0; mt < 4; ++mt)
#pragma unroll
    for (int nt = 0; nt < 2; ++nt)
      acc[mt][nt] = (float4v){0.f, 0.f, 0.f, 0.f};
  if (xw) {
#pragma unroll
    for (int kk = 0; kk < 8; ++kk) {
      short8 af[4];
#pragma unroll
      for (int mt = 0; mt < 4; ++mt)
        af[mt] = *(const short8*)(Ax + roff[mt] + (size_t)kk * kstep);
#pragma unroll
      for (int mt = 0; mt < 4; ++mt) {
        acc[mt][0] = __builtin_amdgcn_mfma_f32_16x16x32_bf16(af[mt], wf[kk * 2 + 0], acc[mt][0], 0, 0, 0);
        acc[mt][1] = __builtin_amdgcn_mfma_f32_16x16x32_bf16(af[mt], wf[kk * 2 + 1], acc[mt][1], 0, 0, 0);
      }
    }
  }
#pragma unroll
  for (int mt = 0; mt < 4; ++mt)
#pragma unroll
    for (int nt = 0; nt < 2; ++nt)
#pragma unroll
      for (int r = 0; r < 4; ++r)
        GP(0, w, 16 * mt + 4 * q + r, 16 * nt + ln) = acc[mt][nt][r];
  __syncthreads();

  for (int t = 0; t < TT; ++t) {
    const int par = t & 1;
    if (xw) {
      // ---- elementwise for step t (reads gp[par], all 8 waves' partials)
      const size_t tb = (size_t)t * BH;
      const size_t hidx = tb + (size_t)p * 512 + (size_t)lane * 8 + 2 * w;
      float hv[2];
#pragma unroll
      for (int s = 0; s < 2; ++s) {
        const int jj = 2 * w + s;
        float iv = bsum[s][0], fv = bsum[s][1], gv = bsum[s][2], ov = bsum[s][3];
#pragma unroll
        for (int ww = 0; ww < 8; ++ww) {
          iv += GP(par, ww, lane, jj);
          fv += GP(par, ww, lane, 8 + jj);
          gv += GP(par, ww, lane, 16 + jj);
          ov += GP(par, ww, lane, 24 + jj);
        }
        const float ig = sigm(iv);
        const float fg = sigm(fv);
        const float gg_ = tanha(gv);
        const float og = sigm(ov);
        const float c = fg * cst[s] + ig * gg_;
        cst[s] = c;
        hv[s] = og * tanha(c);
      }
      if (t < TT - 1) {
        // publish h then per-wave flag byte (no WG-wide barrier on this path)
        unsigned packed = (unsigned)f2bf(hv[0]) | ((unsigned)f2bf(hv[1]) << 16);
        __hip_atomic_store((unsigned*)(hbuf + hidx), packed, __ATOMIC_RELAXED,
                           __HIP_MEMORY_SCOPE_AGENT);
        asm volatile("s_waitcnt vmcnt(0)" ::: "memory"); // this wave's h at LLC
        unsigned char* fb = (unsigned char*)(flags + (size_t)t * GG + p);
        __hip_atomic_store(fb + w, (unsigned char)1, __ATOMIC_RELAXED,
                           __HIP_MEMORY_SCOPE_AGENT);
      }
      // ---- output tail (off critical path)
      {
        float o0, o1;
        if (resf) {
          const float2v r = *(const float2v*)(resf + tb + (size_t)lane * HH + p * 8 + 2 * w);
          o0 = hv[0] + r[0];
          o1 = hv[1] + r[1];
        } else {
          const unsigned rb = *(const unsigned*)(resb + hidx);
          o0 = hv[0] + bf2f((unsigned short)(rb & 0xffff));
          o1 = hv[1] + bf2f((unsigned short)(rb >> 16));
        }
        if (outb)
          *(unsigned*)(outb + hidx) = (unsigned)f2bf(o0) | ((unsigned)f2bf(o1) << 16);
        if (outf) {
          float2v vo; vo[0] = o0; vo[1] = o1;
          *(float2v*)(outf + tb + (size_t)lane * HH + p * 8 + 2 * w) = vo;
        }
      }
      // ---- x-GEMM for step t+1 -> gp[par^1]
      if (t < TT - 1) {
#pragma unroll
        for (int mt = 0; mt < 4; ++mt)
#pragma unroll
          for (int nt = 0; nt < 2; ++nt)
            acc[mt][nt] = (float4v){0.f, 0.f, 0.f, 0.f};
        const unsigned short* Ab = Ax + (size_t)(t + 1) * BH;
#pragma unroll
        for (int kk = 0; kk < 8; ++kk) {
          short8 af[4];
#pragma unroll
          for (int mt = 0; mt < 4; ++mt)
            af[mt] = *(const short8*)(Ab + roff[mt] + (size_t)kk * kstep);
#pragma unroll
          for (int mt = 0; mt < 4; ++mt) {
            acc[mt][0] = __builtin_amdgcn_mfma_f32_16x16x32_bf16(af[mt], wf[kk * 2 + 0], acc[mt][0], 0, 0, 0);
            acc[mt][1] = __builtin_amdgcn_mfma_f32_16x16x32_bf16(af[mt], wf[kk * 2 + 1], acc[mt][1], 0, 0, 0);
          }
        }
#pragma unroll
        for (int mt = 0; mt < 4; ++mt)
#pragma unroll
          for (int nt = 0; nt < 2; ++nt)
#pragma unroll
            for (int r = 0; r < 4; ++r)
              GP(par ^ 1, w, 16 * mt + 4 * q + r, 16 * nt + ln) = acc[mt][nt][r];
      }
    } else {
      // ---- h-wave: consume h[t] published this iteration -> gp[par^1]
      if (t < TT - 1) {
        // poll only this wave's 32 K-producers: one 128B flag line per round
        const int* fl = flags + (size_t)t * GG + 32 * kq;
        for (;;) {
          const int v = __hip_atomic_load(fl + (lane & 31), __ATOMIC_RELAXED,
                                          __HIP_MEMORY_SCOPE_AGENT);
          if (__all(v == 0x01010101)) break;
          __builtin_amdgcn_s_sleep(1);
        }
        __builtin_amdgcn_fence(__ATOMIC_ACQUIRE, "workgroup"); // order only
#pragma unroll
        for (int mt = 0; mt < 4; ++mt)
#pragma unroll
          for (int nt = 0; nt < 2; ++nt)
            acc[mt][nt] = (float4v){0.f, 0.f, 0.f, 0.f};
        const unsigned short* Hb = hbuf + (size_t)t * BH;
#pragma unroll
        for (int kk = 0; kk < 8; ++kk) {
          short8 af[4];
#pragma unroll
          for (int mt = 0; mt < 4; ++mt)
            af[mt] = *(const short8*)(Hb + roff[mt] + (size_t)kk * 2048); // cached
#pragma unroll
          for (int mt = 0; mt < 4; ++mt) {
            acc[mt][0] = __builtin_amdgcn_mfma_f32_16x16x32_bf16(af[mt], wf[kk * 2 + 0], acc[mt][0], 0, 0, 0);
            acc[mt][1] = __builtin_amdgcn_mfma_f32_16x16x32_bf16(af[mt], wf[kk * 2 + 1], acc[mt][1], 0, 0, 0);
          }
        }
#pragma unroll
        for (int mt = 0; mt < 4; ++mt)
#pragma unroll
          for (int nt = 0; nt < 2; ++nt)
#pragma unroll
            for (int r = 0; r < 4; ++r)
              GP(par ^ 1, w, 16 * mt + 4 * q + r, 16 * nt + ln) = acc[mt][nt][r];
      }
    }
    __syncthreads();
  }
}

extern "C" void kernel_launch(void* const* d_in, const int* in_sizes, int n_in,
                              void* d_out, int out_size, void* d_ws, size_t ws_size,
                              hipStream_t stream) {
  const float* x    = (const float*)d_in[0];
  const float* wih5 = (const float*)d_in[1];
  const float* whh5 = (const float*)d_in[2];
  const float* bih5 = (const float*)d_in[3];
  const float* bhh5 = (const float*)d_in[4];
  const float* wih6 = (const float*)d_in[5];
  const float* whh6 = (const float*)d_in[6];
  const float* bih6 = (const float*)d_in[7];
  const float* bhh6 = (const float*)d_in[8];
  float* out = (float*)d_out;

  // ws (96.5 MB): [0,32M) xb (layer5 x, bf16 row-major; REUSED as layer6 hbuf)
  // [32M,64M) out5b ; [64M,96M) hbuf5 ; [96M,+256K) flags (byte-per-wave words)
  char* ws = (char*)d_ws;
  unsigned short* xb    = (unsigned short*)(ws);
  unsigned short* out5b = (unsigned short*)(ws + 33554432);
  unsigned short* hbuf5 = (unsigned short*)(ws + 67108864);
  int* flags            = (int*)(ws + 100663296);

  hipFuncSetAttribute((const void*)lstm_layer,
                      hipFuncAttributeMaxDynamicSharedMemorySize, LDS_BYTES);

  hipMemsetAsync(flags, 0, 2 * TT * GG * sizeof(int), stream);

  const int n8 = TT * BB * HH / 8;
  cvt_f32_bf16<<<dim3((n8 + 255) / 256), dim3(256), 0, stream>>>(x, xb, n8);

  lstm_layer<<<dim3(GG), dim3(512), LDS_BYTES, stream>>>(
      xb, 0, wih5, whh5, bih5, bhh5, x, nullptr, out5b, nullptr, hbuf5, flags);
  lstm_layer<<<dim3(GG), dim3(512), LDS_BYTES, stream>>>(
      out5b, 1, wih6, whh6, bih6, bhh6, nullptr, out5b, nullptr, out,
      xb /* layer6 hbuf */, flags + TT * GG);
}